// Round 1
// baseline (617.661 us; speedup 1.0000x reference)
//
#include <hip/hip_runtime.h>
#include <cstdint>

#define NPROP  48
#define MGRID  216
#define NPT    (NPROP*MGRID)      // 10368 points per batch
#define KPT    2048
#define CFEAT  128
#define R0SQ   0.64f              // 0.8^2 (f32-rounded same as reference)
#define R1SQ   2.56f              // 1.6^2
#define NS0    16
#define NS1    32
#define KRED   (CFEAT*MGRID)      // 27648

// workspace layout (floats)
#define HID_SZ   (96*256)                   // 24576
#define Q0_OFF   24576
#define Q1_OFF   (Q0_OFF + 2*KPT*64)        // +262144
#define POOL_OFF (Q1_OFF + 2*KPT*64)        // +262144 ; pool = [96][27648]

// ---------------------------------------------------------------------------
// K2: Q[s][b][k][o] = b0_s[o] + sum_i W_s[o][i]*kxyz[b][k][i]
//                            + sum_c W_s[o][3+c]*feats[b][c][k]
// grid 2048 blocks x 256 thr : block = (b,s,4 keypoints) x 64 output lanes
// ---------------------------------------------------------------------------
__global__ __launch_bounds__(256) void k_qproj(
    const float* __restrict__ kxyz, const float* __restrict__ feats,
    const float* __restrict__ w0, const float* __restrict__ b0,
    const float* __restrict__ w1, const float* __restrict__ b1,
    float* __restrict__ ws)
{
    __shared__ float wl[64*131];
    int bid  = blockIdx.x;
    int kgrp = bid & 511;
    int s    = (bid >> 9) & 1;
    int b    = bid >> 10;
    const float* W    = s ? w1 : w0;
    const float* bias = s ? b1 : b0;
    for (int i = threadIdx.x; i < 64*131; i += 256) wl[i] = W[i];
    __syncthreads();
    int k = kgrp*4 + (threadIdx.x >> 6);
    int o = threadIdx.x & 63;
    float acc = bias[o];
    const float* kp = kxyz + ((size_t)b*KPT + k)*3;
    acc = fmaf(wl[o*131+0], kp[0], acc);
    acc = fmaf(wl[o*131+1], kp[1], acc);
    acc = fmaf(wl[o*131+2], kp[2], acc);
    const float* f = feats + (size_t)b*CFEAT*KPT + k;
#pragma unroll 8
    for (int c = 0; c < CFEAT; ++c)
        acc = fmaf(wl[o*131+3+c], f[(size_t)c*KPT], acc);
    ws[Q0_OFF + (size_t)s*(2*KPT*64) + ((size_t)b*KPT + k)*64 + o] = acc;
}

// ---------------------------------------------------------------------------
// K3 main: per point (1 wave): ball query + MLP(Q[k]-u) + layer2 + maxpool
// ---------------------------------------------------------------------------
__device__ __forceinline__ float mlp_scale(
    const float* __restrict__ Qb, const int* idxbuf, int navail, int nsamp,
    float u, float bias, const float4* w1, float* hb0, float* hb1, int lane)
{
    float mx = 0.f;
    int nm1 = navail - 1;
    // 2-deep prefetch pipeline of Q rows (coalesced dword per lane)
    float qcur = Qb[((size_t)idxbuf[0] << 6) + lane];
    int t1 = (1 < nm1) ? 1 : nm1;
    float qn1 = Qb[((size_t)idxbuf[t1] << 6) + lane];
#pragma unroll 4
    for (int t = 0; t < nsamp; ++t) {
        int tn2 = t + 2; if (tn2 > nm1) tn2 = nm1;
        float qn2 = Qb[((size_t)idxbuf[tn2] << 6) + lane];
        float h1 = fmaxf(qcur - u, 0.f);
        float* hw = (t & 1) ? hb1 : hb0;
        hw[lane] = h1;                       // lane o writes h1[o]
        __builtin_amdgcn_wave_barrier();     // keep write before the reads
        const float4* hv = (const float4*)hw;
        float a0 = bias, a1 = 0.f, a2 = 0.f, a3 = 0.f;
#pragma unroll
        for (int j = 0; j < 16; ++j) {       // broadcast LDS reads of h1
            float4 h4 = hv[j];
            float4 w  = w1[j];
            a0 = fmaf(w.x, h4.x, a0);
            a1 = fmaf(w.y, h4.y, a1);
            a2 = fmaf(w.z, h4.z, a2);
            a3 = fmaf(w.w, h4.w, a3);
        }
        __builtin_amdgcn_wave_barrier();     // keep reads before next write
        float acc = (a0 + a1) + (a2 + a3);
        mx = fmaxf(mx, fmaxf(acc, 0.f));
        qcur = qn1; qn1 = qn2;
    }
    return mx;
}

__global__ __launch_bounds__(64) void k_main(
    const float* __restrict__ proposals, const float* __restrict__ kxyz,
    const float* __restrict__ grid_noise,
    const float* __restrict__ w00, const float* __restrict__ w01,
    const float* __restrict__ b01,
    const float* __restrict__ w10, const float* __restrict__ w11,
    const float* __restrict__ b11,
    float* __restrict__ ws)
{
    __shared__ int idxs[NS0 + NS1];
    __shared__ __align__(16) float hb[2][64];
    const int lane = threadIdx.x;

    // hoisted per-lane constants: layer2 weight rows + biases + layer1 xyz cols
    float4 w1a[16], w1b[16];
    {
        const float4* wr = (const float4*)(w01 + (size_t)lane*64);
#pragma unroll
        for (int j = 0; j < 16; ++j) w1a[j] = wr[j];
        wr = (const float4*)(w11 + (size_t)lane*64);
#pragma unroll
        for (int j = 0; j < 16; ++j) w1b[j] = wr[j];
    }
    float bias0 = b01[lane], bias1 = b11[lane];
    float a0x = w00[lane*131+0], a0y = w00[lane*131+1], a0z = w00[lane*131+2];
    float a1x = w10[lane*131+0], a1y = w10[lane*131+1], a1z = w10[lane*131+2];
    float* pool = ws + POOL_OFF;

    for (int r = 0; r < 8; ++r) {
        int p   = blockIdx.x*8 + r;          // grid sized exactly: p < 20736
        int b   = p / NPT;
        int rem = p - b*NPT;
        int i   = rem / MGRID;
        int g   = rem - i*MGRID;

        const float* pr = proposals  + ((size_t)b*NPROP + i)*7;
        const float* gn = grid_noise + (((size_t)b*NPROP + i)*MGRID + g)*3;
        float gx = gn[0]*pr[3], gy = gn[1]*pr[4], gz = gn[2]*pr[5];
        float th = pr[6];
        float ss = sinf(th), cc = cosf(th);
        float nx = cc*gx - ss*gy + pr[0];
        float ny = ss*gx + cc*gy + pr[1];
        float nz = gz + pr[2];
        float pn2 = nx*nx + ny*ny + nz*nz;
        float u0 = a0x*nx + a0y*ny + a0z*nz;
        float u1 = a1x*nx + a1y*ny + a1z*nz;

        __syncthreads();                     // LDS reuse fence across points

        // ---- ball query: wave-parallel ordered-first-n selection ----
        int cnt0 = 0, cnt1 = 0;
        const float* kb = kxyz + (size_t)b*KPT*3;
        for (int ck = 0; ck < KPT/64; ++ck) {
            int kk = ck*64 + lane;
            float kx = kb[kk*3+0], ky = kb[kk*3+1], kz = kb[kk*3+2];
            float kn2 = kx*kx + ky*ky + kz*kz;
            float dt  = nx*kx + ny*ky + nz*kz;
            float d2  = fmaf(-2.f, dt, pn2 + kn2);   // |p|^2+|k|^2-2p.k (ref form)
            unsigned long long m0 = __ballot(d2 < R0SQ);
            unsigned long long m1 = __ballot(d2 < R1SQ);
            unsigned long long ltm = (1ull << lane) - 1ull;
            if (cnt0 < NS0 && m0) {
                int pre = __popcll(m0 & ltm);
                if (((m0 >> lane) & 1ull) && cnt0 + pre < NS0) idxs[cnt0+pre] = kk;
            }
            cnt0 += __popcll(m0);
            if (cnt1 < NS1 && m1) {
                int pre = __popcll(m1 & ltm);
                if (((m1 >> lane) & 1ull) && cnt1 + pre < NS1) idxs[NS0+cnt1+pre] = kk;
            }
            cnt1 += __popcll(m1);
            if (cnt0 >= NS0 && cnt1 >= NS1) break;   // wave-uniform
        }
        if (lane == 0) {                     // empty-ball fallback -> keypoint 0
            if (cnt0 == 0) idxs[0]   = 0;
            if (cnt1 == 0) idxs[NS0] = 0;
        }
        __syncthreads();
        int n0 = cnt0 ? min(cnt0, NS0) : 1;
        int n1 = cnt1 ? min(cnt1, NS1) : 1;

        // ---- MLP + maxpool, both scales (clamped duplicates are max-neutral)
        const float* Qb0 = ws + Q0_OFF + (size_t)b*(KPT*64);
        const float* Qb1 = ws + Q1_OFF + (size_t)b*(KPT*64);
        float mx0 = mlp_scale(Qb0, idxs,      n0, NS0, u0, bias0, w1a, hb[0], hb[1], lane);
        float mx1 = mlp_scale(Qb1, idxs+NS0,  n1, NS1, u1, bias1, w1b, hb[0], hb[1], lane);

        // transposed pooled store: pool[row=(b*48+i)][c*216+g], c = lane / 64+lane
        size_t pbase = ((size_t)(b*NPROP + i)*CFEAT)*MGRID + g;
        pool[pbase + (size_t)lane*MGRID]      = mx0;
        pool[pbase + (size_t)(lane+64)*MGRID] = mx1;
    }
}

// ---------------------------------------------------------------------------
// K4: hid[96][256] += A[96][27648] * W0[256][27648]^T   (K-split, atomicAdd)
// grid = 216 ksplits x 2 o-tiles; block 256; per-thread 6r x 8o accumulators
// ---------------------------------------------------------------------------
__global__ __launch_bounds__(256) void k_red0(
    const float* __restrict__ A, const float* __restrict__ w0,
    float* __restrict__ hid)
{
    __shared__ __align__(16) float Al[96*68];
    __shared__ __align__(16) float Bl[128*68];
    int bid = blockIdx.x;
    int ot  = bid & 1;
    int ks  = bid >> 1;                      // 0..215
    int tid = threadIdx.x;
    int tx  = tid & 15, ty = tid >> 4;       // ty in [0,16): 6 rows each
    float acc[6][8] = {};

    for (int chunk = 0; chunk < 2; ++chunk) {
        int kk0 = ks*128 + chunk*64;
#pragma unroll
        for (int j = 0; j < 6; ++j) {        // stage A 96x64
            int f4 = tid + j*256;
            int rr = f4 >> 4, c4 = f4 & 15;
            float4 v = *(const float4*)(A + (size_t)rr*KRED + kk0 + c4*4);
            *(float4*)(Al + rr*68 + c4*4) = v;
        }
#pragma unroll
        for (int j = 0; j < 8; ++j) {        // stage B 128x64
            int f4 = tid + j*256;
            int rr = f4 >> 4, c4 = f4 & 15;
            float4 v = *(const float4*)(w0 + (size_t)(ot*128+rr)*KRED + kk0 + c4*4);
            *(float4*)(Bl + rr*68 + c4*4) = v;
        }
        __syncthreads();
#pragma unroll
        for (int k4 = 0; k4 < 16; ++k4) {
            float4 av[6], bv[8];
#pragma unroll
            for (int q = 0; q < 6; ++q) av[q] = *(const float4*)(Al + (ty*6+q)*68 + k4*4);
#pragma unroll
            for (int u = 0; u < 8; ++u) bv[u] = *(const float4*)(Bl + (u*16+tx)*68 + k4*4);
#pragma unroll
            for (int q = 0; q < 6; ++q)
#pragma unroll
                for (int u = 0; u < 8; ++u) {
                    acc[q][u] = fmaf(av[q].x, bv[u].x, acc[q][u]);
                    acc[q][u] = fmaf(av[q].y, bv[u].y, acc[q][u]);
                    acc[q][u] = fmaf(av[q].z, bv[u].z, acc[q][u]);
                    acc[q][u] = fmaf(av[q].w, bv[u].w, acc[q][u]);
                }
        }
        __syncthreads();
    }
#pragma unroll
    for (int q = 0; q < 6; ++q)
#pragma unroll
        for (int u = 0; u < 8; ++u)
            atomicAdd(hid + (size_t)(ty*6+q)*256 + ot*128 + u*16 + tx, acc[q][u]);
}

// ---------------------------------------------------------------------------
// K5: out = relu(relu(hid + b0) @ W1^T + b1)
// ---------------------------------------------------------------------------
__global__ __launch_bounds__(256) void k_fin(
    const float* __restrict__ hid, const float* __restrict__ rb0,
    const float* __restrict__ w1, const float* __restrict__ rb1,
    float* __restrict__ out)
{
    __shared__ __align__(16) float hbuf[256];
    int r = blockIdx.x, o = threadIdx.x;
    float h = fmaxf(hid[(size_t)r*256 + o] + rb0[o], 0.f);
    hbuf[o] = h;
    __syncthreads();
    float a0 = rb1[o], a1 = 0.f, a2 = 0.f, a3 = 0.f;
    const float4* wrow = (const float4*)(w1 + (size_t)o*256);
    const float4* hv   = (const float4*)hbuf;
#pragma unroll 8
    for (int j = 0; j < 64; ++j) {
        float4 w = wrow[j], x = hv[j];
        a0 = fmaf(w.x, x.x, a0);
        a1 = fmaf(w.y, x.y, a1);
        a2 = fmaf(w.z, x.z, a2);
        a3 = fmaf(w.w, x.w, a3);
    }
    out[(size_t)r*256 + o] = fmaxf((a0 + a1) + (a2 + a3), 0.f);
}

// ---------------------------------------------------------------------------
extern "C" void kernel_launch(void* const* d_in, const int* in_sizes, int n_in,
                              void* d_out, int out_size, void* d_ws, size_t ws_size,
                              hipStream_t stream)
{
    (void)in_sizes; (void)n_in; (void)out_size; (void)ws_size;
    const float* proposals = (const float*)d_in[0];
    const float* kxyz      = (const float*)d_in[1];
    const float* feats     = (const float*)d_in[2];
    const float* gnoise    = (const float*)d_in[3];
    const float* w0_0 = (const float*)d_in[4];
    const float* b0_0 = (const float*)d_in[5];
    const float* w0_1 = (const float*)d_in[6];
    const float* b0_1 = (const float*)d_in[7];
    const float* w1_0 = (const float*)d_in[8];
    const float* b1_0 = (const float*)d_in[9];
    const float* w1_1 = (const float*)d_in[10];
    const float* b1_1 = (const float*)d_in[11];
    const float* rw0  = (const float*)d_in[12];
    const float* rb0  = (const float*)d_in[13];
    const float* rw1  = (const float*)d_in[14];
    const float* rb1  = (const float*)d_in[15];
    float* ws  = (float*)d_ws;
    float* out = (float*)d_out;

    hipMemsetAsync(ws, 0, HID_SZ*sizeof(float), stream);                 // hid = 0
    k_qproj<<<2048, 256, 0, stream>>>(kxyz, feats, w0_0, b0_0, w1_0, b1_0, ws);
    k_main <<<2592,  64, 0, stream>>>(proposals, kxyz, gnoise,
                                      w0_0, w0_1, b0_1, w1_0, w1_1, b1_1, ws);
    k_red0 <<< 432, 256, 0, stream>>>(ws + POOL_OFF, rw0, ws);
    k_fin  <<<  96, 256, 0, stream>>>(ws, rb0, rw1, rb1, out);
}

// Round 2
// 437.585 us; speedup vs baseline: 1.4115x; 1.4115x over previous
//
#include <hip/hip_runtime.h>
#include <cstdint>

#define NPROP  48
#define MGRID  216
#define NPT    (NPROP*MGRID)      // 10368 points per batch
#define KPT    2048
#define CFEAT  128
#define R0SQ   0.64f              // 0.8^2 (f32-rounded same as reference)
#define R1SQ   2.56f              // 1.6^2
#define NS0    16
#define NS1    32
#define KRED   (CFEAT*MGRID)      // 27648
#define NPOINTS (2*NPT)           // 20736

// workspace layout (floats)
#define HID_SZ   (96*256)                   // 24576
#define Q0_OFF   24576
#define Q1_OFF   (Q0_OFF + 2*KPT*64)        // +262144
#define POOL_OFF (Q1_OFF + 2*KPT*64)        // +262144 ; pool = [96][27648]

// ---------------------------------------------------------------------------
// K2: Q[s][b][k][o] = b0_s[o] + sum_i W_s[o][i]*kxyz[b][k][i]
//                            + sum_c W_s[o][3+c]*feats[b][c][k]
// grid 2048 blocks x 256 thr : block = (b,s,4 keypoints) x 64 output lanes
// ---------------------------------------------------------------------------
__global__ __launch_bounds__(256) void k_qproj(
    const float* __restrict__ kxyz, const float* __restrict__ feats,
    const float* __restrict__ w0, const float* __restrict__ b0,
    const float* __restrict__ w1, const float* __restrict__ b1,
    float* __restrict__ ws)
{
    __shared__ float wl[64*131];
    int bid  = blockIdx.x;
    int kgrp = bid & 511;
    int s    = (bid >> 9) & 1;
    int b    = bid >> 10;
    const float* W    = s ? w1 : w0;
    const float* bias = s ? b1 : b0;
    for (int i = threadIdx.x; i < 64*131; i += 256) wl[i] = W[i];
    __syncthreads();
    int k = kgrp*4 + (threadIdx.x >> 6);
    int o = threadIdx.x & 63;
    float acc = bias[o];
    const float* kp = kxyz + ((size_t)b*KPT + k)*3;
    acc = fmaf(wl[o*131+0], kp[0], acc);
    acc = fmaf(wl[o*131+1], kp[1], acc);
    acc = fmaf(wl[o*131+2], kp[2], acc);
    const float* f = feats + (size_t)b*CFEAT*KPT + k;
#pragma unroll 8
    for (int c = 0; c < CFEAT; ++c)
        acc = fmaf(wl[o*131+3+c], f[(size_t)c*KPT], acc);
    ws[Q0_OFF + (size_t)s*(2*KPT*64) + ((size_t)b*KPT + k)*64 + o] = acc;
}

// ---------------------------------------------------------------------------
// K3 main: one WAVE per (point, scale): ball query + MLP(Q[k]-u) + maxpool
// ---------------------------------------------------------------------------
template <int NSAMP>
__device__ __forceinline__ float mlp_scale(
    const float* __restrict__ Qb, const int* idxbuf, int navail,
    float u, float bias, const float4* w1, float* hb0, float* hb1, int lane)
{
    float mx = 0.f;
    int nm1 = navail - 1;
    // 2-deep prefetch pipeline of Q rows (coalesced dword per lane)
    float qcur = Qb[((size_t)idxbuf[0] << 6) + lane];
    int t1 = (1 < nm1) ? 1 : nm1;
    float qn1 = Qb[((size_t)idxbuf[t1] << 6) + lane];
#pragma unroll 4
    for (int t = 0; t < NSAMP; ++t) {
        int tn2 = t + 2; if (tn2 > nm1) tn2 = nm1;
        float qn2 = Qb[((size_t)idxbuf[tn2] << 6) + lane];
        float h1 = fmaxf(qcur - u, 0.f);
        float* hw = (t & 1) ? hb1 : hb0;
        hw[lane] = h1;                       // lane o writes h1[o]
        __builtin_amdgcn_wave_barrier();     // keep write before the reads
        const float4* hv = (const float4*)hw;
        float a0 = bias, a1 = 0.f, a2 = 0.f, a3 = 0.f;
#pragma unroll
        for (int j = 0; j < 16; ++j) {       // broadcast LDS reads of h1
            float4 h4 = hv[j];
            float4 w  = w1[j];
            a0 = fmaf(w.x, h4.x, a0);
            a1 = fmaf(w.y, h4.y, a1);
            a2 = fmaf(w.z, h4.z, a2);
            a3 = fmaf(w.w, h4.w, a3);
        }
        __builtin_amdgcn_wave_barrier();     // keep reads before next write
        float acc = (a0 + a1) + (a2 + a3);
        mx = fmaxf(mx, fmaxf(acc, 0.f));
        qcur = qn1; qn1 = qn2;
    }
    return mx;
}

__global__ __launch_bounds__(256, 4) void k_main(
    const float* __restrict__ proposals, const float* __restrict__ kxyz,
    const float* __restrict__ grid_noise,
    const float* __restrict__ w00, const float* __restrict__ w01,
    const float* __restrict__ b01,
    const float* __restrict__ w10, const float* __restrict__ w11,
    const float* __restrict__ b11,
    float* __restrict__ ws)
{
    __shared__ int idxs[4][32];
    __shared__ __align__(16) float hb[4][2][64];
    const int wid  = threadIdx.x >> 6;
    const int lane = threadIdx.x & 63;

    // scale-grouped task map: blocks [0,5184) = scale 0, [5184,10368) = scale 1
    const int s = (blockIdx.x >= 5184) ? 1 : 0;
    const int p = (blockIdx.x - s*5184)*4 + wid;   // < 20736
    int b   = p / NPT;
    int rem = p - b*NPT;
    int i   = rem / MGRID;
    int g   = rem - i*MGRID;

    // per-scale parameter set
    const float* Wl1  = s ? w10 : w00;   // layer-1 (for xyz columns)
    const float* Wl2  = s ? w11 : w01;   // layer-2 64x64
    const float* bs   = s ? b11 : b01;
    const float  rsq  = s ? R1SQ : R0SQ;
    const int    ns   = s ? NS1  : NS0;

    // hoisted per-lane constants: layer2 weight row + bias + layer1 xyz cols
    float4 w1r[16];
    {
        const float4* wr = (const float4*)(Wl2 + (size_t)lane*64);
#pragma unroll
        for (int j = 0; j < 16; ++j) w1r[j] = wr[j];
    }
    float bias = bs[lane];
    float ax = Wl1[lane*131+0], ay = Wl1[lane*131+1], az = Wl1[lane*131+2];

    const float* pr = proposals  + ((size_t)b*NPROP + i)*7;
    const float* gn = grid_noise + (((size_t)b*NPROP + i)*MGRID + g)*3;
    float gx = gn[0]*pr[3], gy = gn[1]*pr[4], gz = gn[2]*pr[5];
    float th = pr[6];
    float ss = sinf(th), cc = cosf(th);
    float nx = cc*gx - ss*gy + pr[0];
    float ny = ss*gx + cc*gy + pr[1];
    float nz = gz + pr[2];
    float pn2 = nx*nx + ny*ny + nz*nz;
    float u = ax*nx + ay*ny + az*nz;

    // ---- ball query: wave-parallel ordered-first-n selection (single radius)
    int* idx = idxs[wid];
    int cnt = 0;
    const float* kb = kxyz + (size_t)b*KPT*3;
    unsigned long long ltm = (1ull << lane) - 1ull;
    for (int ck = 0; ck < KPT/64; ++ck) {
        int kk = ck*64 + lane;
        float kx = kb[kk*3+0], ky = kb[kk*3+1], kz = kb[kk*3+2];
        float kn2 = kx*kx + ky*ky + kz*kz;
        float dt  = nx*kx + ny*ky + nz*kz;
        float d2  = fmaf(-2.f, dt, pn2 + kn2);   // |p|^2+|k|^2-2p.k (ref form)
        unsigned long long m = __ballot(d2 < rsq);
        if (m) {
            int pre = __popcll(m & ltm);
            if (((m >> lane) & 1ull) && cnt + pre < ns) idx[cnt + pre] = kk;
            cnt += __popcll(m);
            if (cnt >= ns) break;                // wave-uniform
        }
    }
    if (lane == 0 && cnt == 0) idx[0] = 0;       // empty-ball fallback
    asm volatile("s_waitcnt lgkmcnt(0)" ::: "memory");
    __builtin_amdgcn_wave_barrier();
    int navail = cnt ? min(cnt, ns) : 1;

    // ---- MLP + maxpool (clamped duplicate samples are max-neutral)
    const float* Qb = ws + Q0_OFF + (size_t)s*(2*KPT*64) + (size_t)b*(KPT*64);
    float mx;
    if (s == 0)
        mx = mlp_scale<NS0>(Qb, idx, navail, u, bias, w1r, hb[wid][0], hb[wid][1], lane);
    else
        mx = mlp_scale<NS1>(Qb, idx, navail, u, bias, w1r, hb[wid][0], hb[wid][1], lane);

    // transposed pooled store: pool[row=(b*48+i)][(s*64+lane)*216 + g]
    float* pool = ws + POOL_OFF;
    size_t pbase = ((size_t)(b*NPROP + i)*CFEAT)*MGRID + g;
    pool[pbase + (size_t)(s*64 + lane)*MGRID] = mx;
}

// ---------------------------------------------------------------------------
// K4: hid[96][256] += A[96][27648] * W0[256][27648]^T   (K-split, atomicAdd)
// grid = 216 ksplits x 2 o-tiles; block 256; per-thread 6r x 8o accumulators
// ---------------------------------------------------------------------------
__global__ __launch_bounds__(256) void k_red0(
    const float* __restrict__ A, const float* __restrict__ w0,
    float* __restrict__ hid)
{
    __shared__ __align__(16) float Al[96*68];
    __shared__ __align__(16) float Bl[128*68];
    int bid = blockIdx.x;
    int ot  = bid & 1;
    int ks  = bid >> 1;                      // 0..215
    int tid = threadIdx.x;
    int tx  = tid & 15, ty = tid >> 4;       // ty in [0,16): 6 rows each
    float acc[6][8] = {};

    for (int chunk = 0; chunk < 2; ++chunk) {
        int kk0 = ks*128 + chunk*64;
#pragma unroll
        for (int j = 0; j < 6; ++j) {        // stage A 96x64
            int f4 = tid + j*256;
            int rr = f4 >> 4, c4 = f4 & 15;
            float4 v = *(const float4*)(A + (size_t)rr*KRED + kk0 + c4*4);
            *(float4*)(Al + rr*68 + c4*4) = v;
        }
#pragma unroll
        for (int j = 0; j < 8; ++j) {        // stage B 128x64
            int f4 = tid + j*256;
            int rr = f4 >> 4, c4 = f4 & 15;
            float4 v = *(const float4*)(w0 + (size_t)(ot*128+rr)*KRED + kk0 + c4*4);
            *(float4*)(Bl + rr*68 + c4*4) = v;
        }
        __syncthreads();
#pragma unroll
        for (int k4 = 0; k4 < 16; ++k4) {
            float4 av[6], bv[8];
#pragma unroll
            for (int q = 0; q < 6; ++q) av[q] = *(const float4*)(Al + (ty*6+q)*68 + k4*4);
#pragma unroll
            for (int u = 0; u < 8; ++u) bv[u] = *(const float4*)(Bl + (u*16+tx)*68 + k4*4);
#pragma unroll
            for (int q = 0; q < 6; ++q)
#pragma unroll
                for (int u = 0; u < 8; ++u) {
                    acc[q][u] = fmaf(av[q].x, bv[u].x, acc[q][u]);
                    acc[q][u] = fmaf(av[q].y, bv[u].y, acc[q][u]);
                    acc[q][u] = fmaf(av[q].z, bv[u].z, acc[q][u]);
                    acc[q][u] = fmaf(av[q].w, bv[u].w, acc[q][u]);
                }
        }
        __syncthreads();
    }
#pragma unroll
    for (int q = 0; q < 6; ++q)
#pragma unroll
        for (int u = 0; u < 8; ++u)
            atomicAdd(hid + (size_t)(ty*6+q)*256 + ot*128 + u*16 + tx, acc[q][u]);
}

// ---------------------------------------------------------------------------
// K5: out = relu(relu(hid + b0) @ W1^T + b1)
// ---------------------------------------------------------------------------
__global__ __launch_bounds__(256) void k_fin(
    const float* __restrict__ hid, const float* __restrict__ rb0,
    const float* __restrict__ w1, const float* __restrict__ rb1,
    float* __restrict__ out)
{
    __shared__ __align__(16) float hbuf[256];
    int r = blockIdx.x, o = threadIdx.x;
    float h = fmaxf(hid[(size_t)r*256 + o] + rb0[o], 0.f);
    hbuf[o] = h;
    __syncthreads();
    float a0 = rb1[o], a1 = 0.f, a2 = 0.f, a3 = 0.f;
    const float4* wrow = (const float4*)(w1 + (size_t)o*256);
    const float4* hv   = (const float4*)hbuf;
#pragma unroll 8
    for (int j = 0; j < 64; ++j) {
        float4 w = wrow[j], x = hv[j];
        a0 = fmaf(w.x, x.x, a0);
        a1 = fmaf(w.y, x.y, a1);
        a2 = fmaf(w.z, x.z, a2);
        a3 = fmaf(w.w, x.w, a3);
    }
    out[(size_t)r*256 + o] = fmaxf((a0 + a1) + (a2 + a3), 0.f);
}

// ---------------------------------------------------------------------------
extern "C" void kernel_launch(void* const* d_in, const int* in_sizes, int n_in,
                              void* d_out, int out_size, void* d_ws, size_t ws_size,
                              hipStream_t stream)
{
    (void)in_sizes; (void)n_in; (void)out_size; (void)ws_size;
    const float* proposals = (const float*)d_in[0];
    const float* kxyz      = (const float*)d_in[1];
    const float* feats     = (const float*)d_in[2];
    const float* gnoise    = (const float*)d_in[3];
    const float* w0_0 = (const float*)d_in[4];
    const float* b0_0 = (const float*)d_in[5];
    const float* w0_1 = (const float*)d_in[6];
    const float* b0_1 = (const float*)d_in[7];
    const float* w1_0 = (const float*)d_in[8];
    const float* b1_0 = (const float*)d_in[9];
    const float* w1_1 = (const float*)d_in[10];
    const float* b1_1 = (const float*)d_in[11];
    const float* rw0  = (const float*)d_in[12];
    const float* rb0  = (const float*)d_in[13];
    const float* rw1  = (const float*)d_in[14];
    const float* rb1  = (const float*)d_in[15];
    float* ws  = (float*)d_ws;
    float* out = (float*)d_out;

    hipMemsetAsync(ws, 0, HID_SZ*sizeof(float), stream);                 // hid = 0
    k_qproj<<<2048, 256, 0, stream>>>(kxyz, feats, w0_0, b0_0, w1_0, b1_0, ws);
    k_main <<<10368, 256, 0, stream>>>(proposals, kxyz, gnoise,
                                       w0_0, w0_1, b0_1, w1_0, w1_1, b1_1, ws);
    k_red0 <<< 432, 256, 0, stream>>>(ws + POOL_OFF, rw0, ws);
    k_fin  <<<  96, 256, 0, stream>>>(ws, rb0, rw1, rb1, out);
}